// Round 5
// baseline (135.460 us; speedup 1.0000x reference)
//
#include <hip/hip_runtime.h>

#define IN_CH  64
#define OUT_CH 32
#define BLOCK  8

using f32x4 = __attribute__((ext_vector_type(4))) float;

// ws layout: argmax M*4 | wt(bf16) 32KB

// wt bf16 layout: u32 index = ((c4*8 + j)*32 + o)*2 + p
// each u32 holds bf16 pair for channels (c4*4 + 2p, c4*4 + 2p + 1)
__global__ void k_transpose_bf16(const float* __restrict__ w, unsigned* __restrict__ wt) {
    int d = blockIdx.x * 256 + threadIdx.x;          // 8192 u32 words
    if (d >= BLOCK * OUT_CH * IN_CH / 2) return;
    int p  = d & 1;
    int o  = (d >> 1) & 31;
    int j  = (d >> 6) & 7;
    int c4 = d >> 9;
    int c  = c4 * 4 + p * 2;
    float f0 = w[(o * BLOCK + j) * IN_CH + c];
    float f1 = w[(o * BLOCK + j) * IN_CH + c + 1];
    auto cvt = [](float f) -> unsigned {             // RN-even f32 -> bf16
        unsigned u = __float_as_uint(f);
        return (u + 0x7fffu + ((u >> 16) & 1u)) >> 16;
    };
    wt[d] = cvt(f0) | (cvt(f1) << 16);
}

// argmax[m] is monotone non-decreasing, so a stale (L2-cached) read is a valid
// lower bound: skipping when argmax[m] >= t is ALWAYS correct; atomicMax
// handles any race we don't skip. Dispatch boundaries make prior dispatches'
// atomics visible to the plain filter reads, so later passes filter ~hard.
__global__ void k_scatter_range(const int* __restrict__ pair, int* __restrict__ argmax,
                                int N, int jhi, int jlo, int flip) {
    int n = blockIdx.x * 256 + threadIdx.x;
    if (n >= N) return;
    if (flip) n = N - 1 - n;        // high-t first (execution order ~ blockIdx)
    for (int j = jhi; j >= jlo; --j) {
        int t = j * N + n;
        int m = pair[t];
        if (m >= 0 && argmax[m] < t)
            atomicMax(&argmax[m], t);
    }
}

__global__ __launch_bounds__(512, 8) void k_compute(
        const float* __restrict__ x, const uint2* __restrict__ wt,
        const int* __restrict__ argmax, float* __restrict__ out, int M, int N) {
    __shared__ uint2 Wl[4096];                       // 32 KB: full weights, bf16
    for (int i = threadIdx.x; i < 4096; i += 512) Wl[i] = wt[i];
    __syncthreads();

    int lane = threadIdx.x & 63;
    int o    = lane & 31;
    int h    = lane >> 5;
    int gw   = (blockIdx.x * 512 + threadIdx.x) >> 6;   // global wave id
    unsigned uN = (unsigned)N;

    int base = gw * 32;
    if (base >= M) return;
    int nrows = min(32, M - base);

    int t64 = (lane < nrows) ? argmax[base + lane] : -1;   // coalesced meta-load

    for (int r = 0; r < nrows; ++r) {
        int t = __shfl(t64, r);
        // branch-free decode; invalid rows read row 0 and mask at the end
        unsigned j = 0; int n = 0;
        if (t >= 0) { j = (unsigned)t / uN; n = t - (int)(j * uN); }
        const f32x4* xr = (const f32x4*)(x + (size_t)n * IN_CH) + h * 8;
        f32x4 xv[8];
#pragma unroll
        for (int k = 0; k < 8; ++k) xv[k] = xr[k];
        // Pin all 8 gathers in registers: forces 8 loads in flight -> ONE
        // L2/L3 round trip per row instead of 8 serial ones (VGPR 28 -> ~60).
        asm volatile("" : "+v"(xv[0]), "+v"(xv[1]), "+v"(xv[2]), "+v"(xv[3]),
                          "+v"(xv[4]), "+v"(xv[5]), "+v"(xv[6]), "+v"(xv[7]));
        const uint2* wp = Wl + h * 2048 + (int)j * 32 + o;
        float ax = 0.f, ay = 0.f, az = 0.f, aw = 0.f;
#pragma unroll
        for (int k = 0; k < 8; ++k) {
            uint2 wv = wp[k * 256];                  // +k on c4 -> +8*32 uint2
            float w0 = __uint_as_float(wv.x << 16);
            float w1 = __uint_as_float(wv.x & 0xffff0000u);
            float w2 = __uint_as_float(wv.y << 16);
            float w3 = __uint_as_float(wv.y & 0xffff0000u);
            ax = fmaf(w0, xv[k][0], ax);
            ay = fmaf(w1, xv[k][1], ay);
            az = fmaf(w2, xv[k][2], az);
            aw = fmaf(w3, xv[k][3], aw);
        }
        float s = (ax + ay) + (az + aw);
        s += __shfl_xor(s, 32);                      // combine c-halves
        if (t < 0) s = 0.f;
        if (h == 0)
            out[(size_t)(base + r) * OUT_CH + o] = s;
    }
}

extern "C" void kernel_launch(void* const* d_in, const int* in_sizes, int n_in,
                              void* d_out, int out_size, void* d_ws, size_t ws_size,
                              hipStream_t stream) {
    const float* x    = (const float*)d_in[0];
    const float* w    = (const float*)d_in[1];
    const int*   pair = (const int*)d_in[2];
    int N = in_sizes[0] / IN_CH;     // 400000
    int M = out_size / OUT_CH;       // 200000

    char*     ws     = (char*)d_ws;
    int*      argmax = (int*)ws;
    unsigned* wt     = (unsigned*)(ws + (size_t)M * 4);

    hipMemsetAsync(argmax, 0xFF, (size_t)M * 4, stream);   // -1

    int gN = (N + 255) / 256;
    k_transpose_bf16<<<(BLOCK * OUT_CH * IN_CH / 2 + 255) / 256, 256, 0, stream>>>(w, wt);
    k_scatter_range<<<gN, 256, 0, stream>>>(pair, argmax, N, 7, 7, 1); // j=7, high-t first
    k_scatter_range<<<gN, 256, 0, stream>>>(pair, argmax, N, 6, 6, 0); // j=6, sees j=7
    k_scatter_range<<<gN, 256, 0, stream>>>(pair, argmax, N, 5, 0, 0); // rest, ~98% filtered

    int waves  = (M + 31) / 32;
    int blocks = (waves + 7) / 8;
    k_compute<<<blocks, 512, 0, stream>>>(x, (const uint2*)wt, argmax,
                                          (float*)d_out, M, N);
}

// Round 6
// 101.162 us; speedup vs baseline: 1.3390x; 1.3390x over previous
//
#include <hip/hip_runtime.h>

#define IN_CH  64
#define OUT_CH 32
#define BLOCK  8
#define ROWS   8     // rows per LDS tile

// ws layout: argmax M*4 | wt(bf16, uint4 entries) 32KB

__device__ __forceinline__ float bflo(unsigned u) { return __uint_as_float(u << 16); }
__device__ __forceinline__ float bfhi(unsigned u) { return __uint_as_float(u & 0xffff0000u); }

// wt u32 word index d = ((c8*8 + j)*32 + o)*4 + q ; word holds bf16 pair for
// channels (c8*8 + 2q, c8*8 + 2q + 1). uint4 entry (c8,j,o) = channels c8*8..+7.
__global__ void k_transpose_bf16(const float* __restrict__ w, unsigned* __restrict__ wt) {
    int d = blockIdx.x * 256 + threadIdx.x;          // 8192 u32 words
    if (d >= BLOCK * OUT_CH * IN_CH / 2) return;
    int q  = d & 3;
    int o  = (d >> 2) & 31;
    int j  = (d >> 7) & 7;
    int c8 = d >> 10;
    int c  = c8 * 8 + q * 2;
    float f0 = w[(o * BLOCK + j) * IN_CH + c];
    float f1 = w[(o * BLOCK + j) * IN_CH + c + 1];
    auto cvt = [](float f) -> unsigned {             // RN-even f32 -> bf16
        unsigned u = __float_as_uint(f);
        return (u + 0x7fffu + ((u >> 16) & 1u)) >> 16;
    };
    wt[d] = cvt(f0) | (cvt(f1) << 16);
}

// argmax[m] monotone non-decreasing => stale read is a valid lower bound;
// filtered atomicMax is always correct. Dispatch splits make earlier passes'
// results visible so later passes filter ~all their atomics.
__global__ void k_scatter_range(const int* __restrict__ pair, int* __restrict__ argmax,
                                int N, int jhi, int jlo, int flip) {
    int n = blockIdx.x * 256 + threadIdx.x;
    if (n >= N) return;
    if (flip) n = N - 1 - n;
    for (int j = jhi; j >= jlo; --j) {
        int t = j * N + n;
        int m = pair[t];
        if (m >= 0 && argmax[m] < t)
            atomicMax(&argmax[m], t);
    }
}

__global__ __launch_bounds__(512, 4) void k_compute(
        const float* __restrict__ x, const uint4* __restrict__ wt,
        const int* __restrict__ argmax, float* __restrict__ out, int M, int N) {
    __shared__ uint4 Wl[2048];                             // 32 KB weights (bf16)
    __shared__ __align__(16) float Xl[8][2][ROWS * 64];    // 32 KB: per-wave dbuf x tiles
    for (int i = threadIdx.x; i < 2048; i += 512) Wl[i] = wt[i];
    __syncthreads();

    const int lane = threadIdx.x & 63;
    const int o    = lane & 31;
    const int h    = lane >> 5;
    const int wv   = threadIdx.x >> 6;
    const unsigned uN = (unsigned)N;

    int gw   = blockIdx.x * 8 + wv;
    int base = gw * 64;
    if (base >= M) return;
    int nrows = min(64, M - base);

    // per-lane row metadata (decoded ONCE): lane owns row base+lane
    int t0 = ((base + lane) < M) ? argmax[base + lane] : -1;
    int jn = 8, nn = 0;                      // jn==8 marks invalid row
    if (t0 >= 0) {
        unsigned j = (unsigned)t0 / uN;
        nn = t0 - (int)(j * uN);
        jn = (int)j;
    }

    int ntiles = (nrows + ROWS - 1) / ROWS;
    float ld[ROWS];

    // prologue: issue tile 0 gathers — one coalesced 256B row per instr,
    // 8 independent loads in flight (8 VGPRs)
#pragma unroll
    for (int r = 0; r < ROWS; ++r) {
        int n = __shfl(nn, r);
        ld[r] = x[(size_t)n * IN_CH + lane];
    }

    for (int tile = 0; tile < ntiles; ++tile) {
        float* buf = &Xl[wv][tile & 1][0];
        // drain gathers (compiler emits vmcnt) and stage tile into LDS
#pragma unroll
        for (int r = 0; r < ROWS; ++r)
            buf[r * 64 + lane] = ld[r];

        // issue next tile's gathers — overlaps with this tile's compute
        if (tile + 1 < ntiles) {
            int nb = (tile + 1) * ROWS;
#pragma unroll
            for (int r = 0; r < ROWS; ++r) {
                int n = __shfl(nn, nb + r);
                ld[r] = x[(size_t)n * IN_CH + lane];
            }
        }

        // wave-private LDS: no barrier needed, just drain ds_writes
        asm volatile("s_waitcnt lgkmcnt(0)" ::: "memory");

#pragma unroll 2
        for (int r = 0; r < ROWS; ++r) {
            int grow = tile * ROWS + r;
            int jc   = __shfl(jn, grow);
            const float4* xp = (const float4*)(buf + r * 64) + h * 8;  // bcast reads
            const uint4*  wp = Wl + h * 1024 + (jc & 7) * 32 + o;
            float ax = 0.f, ay = 0.f, az = 0.f, aw = 0.f;
#pragma unroll
            for (int k = 0; k < 4; ++k) {
                uint4  wq  = wp[k * 256];
                float4 xv0 = xp[k * 2];
                float4 xv1 = xp[k * 2 + 1];
                ax = fmaf(bflo(wq.x), xv0.x, ax);
                ay = fmaf(bfhi(wq.x), xv0.y, ay);
                az = fmaf(bflo(wq.y), xv0.z, az);
                aw = fmaf(bfhi(wq.y), xv0.w, aw);
                ax = fmaf(bflo(wq.z), xv1.x, ax);
                ay = fmaf(bfhi(wq.z), xv1.y, ay);
                az = fmaf(bflo(wq.w), xv1.z, az);
                aw = fmaf(bfhi(wq.w), xv1.w, aw);
            }
            float s = (ax + ay) + (az + aw);
            s += __shfl_xor(s, 32);              // combine c-halves
            if (jc == 8) s = 0.f;                // unmapped row -> exact 0
            if (h == 0 && grow < nrows)
                out[(size_t)(base + grow) * OUT_CH + o] = s;
        }
    }
}

extern "C" void kernel_launch(void* const* d_in, const int* in_sizes, int n_in,
                              void* d_out, int out_size, void* d_ws, size_t ws_size,
                              hipStream_t stream) {
    const float* x    = (const float*)d_in[0];
    const float* w    = (const float*)d_in[1];
    const int*   pair = (const int*)d_in[2];
    int N = in_sizes[0] / IN_CH;     // 400000
    int M = out_size / OUT_CH;       // 200000

    char*     ws     = (char*)d_ws;
    int*      argmax = (int*)ws;
    unsigned* wt     = (unsigned*)(ws + (size_t)M * 4);

    hipMemsetAsync(argmax, 0xFF, (size_t)M * 4, stream);   // -1

    int gN = (N + 255) / 256;
    k_transpose_bf16<<<(BLOCK * OUT_CH * IN_CH / 2 + 255) / 256, 256, 0, stream>>>(w, wt);
    k_scatter_range<<<gN, 256, 0, stream>>>(pair, argmax, N, 7, 7, 1); // j=7, high-t first
    k_scatter_range<<<gN, 256, 0, stream>>>(pair, argmax, N, 6, 6, 0); // j=6, sees j=7
    k_scatter_range<<<gN, 256, 0, stream>>>(pair, argmax, N, 5, 0, 0); // rest, ~98% filtered

    int waves  = (M + 63) / 64;
    int blocks = (waves + 7) / 8;
    k_compute<<<blocks, 512, 0, stream>>>(x, (const uint4*)wt, argmax,
                                          (float*)d_out, M, N);
}

// Round 7
// 100.490 us; speedup vs baseline: 1.3480x; 1.0067x over previous
//
#include <hip/hip_runtime.h>

#define IN_CH  64
#define OUT_CH 32
#define BLOCK  8
#define ROWS   8     // rows per LDS tile

// ws layout: argmax M*4 | wt(bf16, uint4 entries) 32KB

__device__ __forceinline__ float bflo(unsigned u) { return __uint_as_float(u << 16); }
__device__ __forceinline__ float bfhi(unsigned u) { return __uint_as_float(u & 0xffff0000u); }

// rocclr's fillBuffer runs 800KB at 14 GB/s (58us, latency-bound tiny grid);
// this does it in ~4us.
__global__ void k_fill_m1(int4* __restrict__ p, int n4) {
    int i = blockIdx.x * 256 + threadIdx.x;
    if (i < n4) p[i] = make_int4(-1, -1, -1, -1);
}

// wt u32 word index d = ((c8*8 + j)*32 + o)*4 + q ; word holds bf16 pair for
// channels (c8*8 + 2q, c8*8 + 2q + 1). uint4 entry (c8,j,o) = channels c8*8..+7.
__global__ void k_transpose_bf16(const float* __restrict__ w, unsigned* __restrict__ wt) {
    int d = blockIdx.x * 256 + threadIdx.x;          // 8192 u32 words
    if (d >= BLOCK * OUT_CH * IN_CH / 2) return;
    int q  = d & 3;
    int o  = (d >> 2) & 31;
    int j  = (d >> 7) & 7;
    int c8 = d >> 10;
    int c  = c8 * 8 + q * 2;
    float f0 = w[(o * BLOCK + j) * IN_CH + c];
    float f1 = w[(o * BLOCK + j) * IN_CH + c + 1];
    auto cvt = [](float f) -> unsigned {             // RN-even f32 -> bf16
        unsigned u = __float_as_uint(f);
        return (u + 0x7fffu + ((u >> 16) & 1u)) >> 16;
    };
    wt[d] = cvt(f0) | (cvt(f1) << 16);
}

// argmax[m] monotone non-decreasing => stale read is a valid lower bound;
// filtered atomicMax is always correct. Dispatch splits make earlier passes'
// results visible so later passes filter ~all their atomics.
__global__ void k_scatter_range(const int* __restrict__ pair, int* __restrict__ argmax,
                                int N, int jhi, int jlo, int flip) {
    int n = blockIdx.x * 256 + threadIdx.x;
    if (n >= N) return;
    if (flip) n = N - 1 - n;
    for (int j = jhi; j >= jlo; --j) {
        int t = j * N + n;
        int m = pair[t];
        if (m >= 0 && argmax[m] < t)
            atomicMax(&argmax[m], t);
    }
}

__global__ __launch_bounds__(512, 4) void k_compute(
        const float* __restrict__ x, const uint4* __restrict__ wt,
        const int* __restrict__ argmax, float* __restrict__ out, int M, int N) {
    __shared__ uint4 Wl[2048];                             // 32 KB weights (bf16)
    __shared__ __align__(16) float Xl[8][2][ROWS * 64];    // 32 KB: per-wave dbuf x tiles
    for (int i = threadIdx.x; i < 2048; i += 512) Wl[i] = wt[i];
    __syncthreads();

    const int lane = threadIdx.x & 63;
    const int o    = lane & 31;
    const int h    = lane >> 5;
    const int wv   = threadIdx.x >> 6;
    const unsigned uN = (unsigned)N;

    int gw   = blockIdx.x * 8 + wv;
    int base = gw * 64;
    if (base >= M) return;
    int nrows = min(64, M - base);

    // per-lane row metadata (decoded ONCE): lane owns row base+lane
    int t0 = ((base + lane) < M) ? argmax[base + lane] : -1;
    int jn = 8, nn = 0;                      // jn==8 marks invalid row
    if (t0 >= 0) {
        unsigned j = (unsigned)t0 / uN;
        nn = t0 - (int)(j * uN);
        jn = (int)j;
    }

    int ntiles = (nrows + ROWS - 1) / ROWS;
    float ld[ROWS];

    // prologue: issue tile 0 gathers — one coalesced 256B row per instr,
    // 8 independent loads in flight (8 VGPRs)
#pragma unroll
    for (int r = 0; r < ROWS; ++r) {
        int n = __shfl(nn, r);
        ld[r] = x[(size_t)n * IN_CH + lane];
    }

    for (int tile = 0; tile < ntiles; ++tile) {
        float* buf = &Xl[wv][tile & 1][0];
        // drain gathers (compiler emits vmcnt) and stage tile into LDS
#pragma unroll
        for (int r = 0; r < ROWS; ++r)
            buf[r * 64 + lane] = ld[r];

        // issue next tile's gathers — overlaps with this tile's compute
        if (tile + 1 < ntiles) {
            int nb = (tile + 1) * ROWS;
#pragma unroll
            for (int r = 0; r < ROWS; ++r) {
                int n = __shfl(nn, nb + r);
                ld[r] = x[(size_t)n * IN_CH + lane];
            }
        }

        // wave-private LDS: no barrier needed, just drain ds_writes
        asm volatile("s_waitcnt lgkmcnt(0)" ::: "memory");

#pragma unroll 2
        for (int r = 0; r < ROWS; ++r) {
            int grow = tile * ROWS + r;
            int jc   = __shfl(jn, grow);
            const float4* xp = (const float4*)(buf + r * 64) + h * 8;  // bcast reads
            const uint4*  wp = Wl + h * 1024 + (jc & 7) * 32 + o;
            float ax = 0.f, ay = 0.f, az = 0.f, aw = 0.f;
#pragma unroll
            for (int k = 0; k < 4; ++k) {
                uint4  wq  = wp[k * 256];
                float4 xv0 = xp[k * 2];
                float4 xv1 = xp[k * 2 + 1];
                ax = fmaf(bflo(wq.x), xv0.x, ax);
                ay = fmaf(bfhi(wq.x), xv0.y, ay);
                az = fmaf(bflo(wq.y), xv0.z, az);
                aw = fmaf(bfhi(wq.y), xv0.w, aw);
                ax = fmaf(bflo(wq.z), xv1.x, ax);
                ay = fmaf(bfhi(wq.z), xv1.y, ay);
                az = fmaf(bflo(wq.w), xv1.z, az);
                aw = fmaf(bfhi(wq.w), xv1.w, aw);
            }
            float s = (ax + ay) + (az + aw);
            s += __shfl_xor(s, 32);              // combine c-halves
            if (jc == 8) s = 0.f;                // unmapped row -> exact 0
            if (h == 0 && grow < nrows)
                out[(size_t)(base + grow) * OUT_CH + o] = s;
        }
    }
}

extern "C" void kernel_launch(void* const* d_in, const int* in_sizes, int n_in,
                              void* d_out, int out_size, void* d_ws, size_t ws_size,
                              hipStream_t stream) {
    const float* x    = (const float*)d_in[0];
    const float* w    = (const float*)d_in[1];
    const int*   pair = (const int*)d_in[2];
    int N = in_sizes[0] / IN_CH;     // 400000
    int M = out_size / OUT_CH;       // 200000

    char*     ws     = (char*)d_ws;
    int*      argmax = (int*)ws;
    unsigned* wt     = (unsigned*)(ws + (size_t)M * 4);

    int n4 = M / 4;                  // M % 4 == 0
    k_fill_m1<<<(n4 + 255) / 256, 256, 0, stream>>>((int4*)argmax, n4);

    int gN = (N + 255) / 256;
    k_transpose_bf16<<<(BLOCK * OUT_CH * IN_CH / 2 + 255) / 256, 256, 0, stream>>>(w, wt);
    k_scatter_range<<<gN, 256, 0, stream>>>(pair, argmax, N, 7, 7, 1); // j=7, high-t first
    k_scatter_range<<<gN, 256, 0, stream>>>(pair, argmax, N, 6, 6, 0); // j=6, sees j=7
    k_scatter_range<<<gN, 256, 0, stream>>>(pair, argmax, N, 5, 0, 0); // rest, ~98% filtered

    int waves  = (M + 63) / 64;
    int blocks = (waves + 7) / 8;
    k_compute<<<blocks, 512, 0, stream>>>(x, (const uint4*)wt, argmax,
                                          (float*)d_out, M, N);
}

// Round 8
// 96.340 us; speedup vs baseline: 1.4061x; 1.0431x over previous
//
#include <hip/hip_runtime.h>

#define IN_CH  64
#define OUT_CH 32
#define BLOCK  8
#define ROWS   8     // rows per LDS tile

// ws layout: argmax M*4 | wt(bf16, uint4 entries) 32KB

__device__ __forceinline__ float bflo(unsigned u) { return __uint_as_float(u << 16); }
__device__ __forceinline__ float bfhi(unsigned u) { return __uint_as_float(u & 0xffff0000u); }

// fused: argmax := -1 (int4 stores) + weight transpose -> bf16
// wt u32 word index d = ((c8*8 + j)*32 + o)*4 + q ; word holds bf16 pair for
// channels (c8*8 + 2q, c8*8 + 2q + 1). uint4 entry (c8,j,o) = channels c8*8..+7.
__global__ void k_prep(const float* __restrict__ w, unsigned* __restrict__ wt,
                       int4* __restrict__ argmax4, int n4) {
    int i = blockIdx.x * 256 + threadIdx.x;
    if (i < n4) argmax4[i] = make_int4(-1, -1, -1, -1);
    if (i < BLOCK * OUT_CH * IN_CH / 2) {
        int q  = i & 3;
        int o  = (i >> 2) & 31;
        int j  = (i >> 7) & 7;
        int c8 = i >> 10;
        int c  = c8 * 8 + q * 2;
        float f0 = w[(o * BLOCK + j) * IN_CH + c];
        float f1 = w[(o * BLOCK + j) * IN_CH + c + 1];
        auto cvt = [](float f) -> unsigned {             // RN-even f32 -> bf16
            unsigned u = __float_as_uint(f);
            return (u + 0x7fffu + ((u >> 16) & 1u)) >> 16;
        };
        wt[i] = cvt(f0) | (cvt(f1) << 16);
    }
}

// argmax[m] monotone non-decreasing => stale read is a valid lower bound;
// filtered atomicMax is always correct. Dispatch split makes pass-1 results
// visible so pass-2 filters ~all its atomics.
__global__ void k_scatter_range(const int* __restrict__ pair, int* __restrict__ argmax,
                                int N, int jhi, int jlo, int flip) {
    int n = blockIdx.x * 256 + threadIdx.x;
    if (n >= N) return;
    if (flip) n = N - 1 - n;        // high-t first (execution order ~ blockIdx)
    for (int j = jhi; j >= jlo; --j) {
        int t = j * N + n;
        int m = pair[t];
        if (m >= 0 && argmax[m] < t)
            atomicMax(&argmax[m], t);
    }
}

__device__ __forceinline__ float row_dot(const float* __restrict__ buf, int r, int jcv,
                                         const uint4* __restrict__ Wl, int o, int h) {
    const float4* xp = (const float4*)(buf + r * 64) + h * 8;       // bcast reads
    const uint4*  wp = Wl + h * 1024 + (jcv & 7) * 32 + o;          // SGPR offset
    float ax = 0.f, ay = 0.f, az = 0.f, aw = 0.f;
#pragma unroll
    for (int k = 0; k < 4; ++k) {
        uint4  wq  = wp[k * 256];
        float4 xv0 = xp[k * 2];
        float4 xv1 = xp[k * 2 + 1];
        ax = fmaf(bflo(wq.x), xv0.x, ax);
        ay = fmaf(bfhi(wq.x), xv0.y, ay);
        az = fmaf(bflo(wq.y), xv0.z, az);
        aw = fmaf(bfhi(wq.y), xv0.w, aw);
        ax = fmaf(bflo(wq.z), xv1.x, ax);
        ay = fmaf(bfhi(wq.z), xv1.y, ay);
        az = fmaf(bflo(wq.w), xv1.z, az);
        aw = fmaf(bfhi(wq.w), xv1.w, aw);
    }
    float s = (ax + ay) + (az + aw);
    s += __shfl_xor(s, 32);              // combine c-halves (permlane32 swap)
    return (jcv == 8) ? 0.f : s;         // unmapped row -> exact 0
}

__global__ __launch_bounds__(512, 4) void k_compute(
        const float* __restrict__ x, const uint4* __restrict__ wt,
        const int* __restrict__ argmax, float* __restrict__ out, int M, int N) {
    __shared__ uint4 Wl[2048];                             // 32 KB weights (bf16)
    __shared__ __align__(16) float Xl[8][2][ROWS * 64];    // 32 KB: per-wave dbuf x tiles
    for (int i = threadIdx.x; i < 2048; i += 512) Wl[i] = wt[i];
    __syncthreads();

    const int lane = threadIdx.x & 63;
    const int o    = lane & 31;
    const int h    = lane >> 5;
    const int wv   = threadIdx.x >> 6;
    const unsigned uN = (unsigned)N;

    int gw   = blockIdx.x * 8 + wv;
    int base = gw * 64;
    if (base >= M) return;
    int nrows = min(64, M - base);

    // per-lane row metadata (decoded ONCE): lane owns row base+lane
    int t0 = ((base + lane) < M) ? argmax[base + lane] : -1;
    int jn = 8, nn = 0;                      // jn==8 marks invalid row
    if (t0 >= 0) {
        unsigned j = (unsigned)t0 / uN;
        nn = t0 - (int)(j * uN);
        jn = (int)j;
    }

    int ntiles = (nrows + ROWS - 1) / ROWS;
    float ld[ROWS];

    // prologue: tile-0 gathers. One coalesced 256B row per instr; row index via
    // v_readlane (SALU, SGPR base) -- NO ds_bpermute in any address path.
#pragma unroll
    for (int r = 0; r < ROWS; ++r) {
        int n = __builtin_amdgcn_readlane(nn, r);
        ld[r] = x[(size_t)n * IN_CH + lane];
    }

    for (int tile = 0; tile < ntiles; ++tile) {
        float* buf = &Xl[wv][tile & 1][0];

        // this tile's j's -> SGPRs, ahead of the LDS wait
        int jc[ROWS];
#pragma unroll
        for (int r = 0; r < ROWS; ++r)
            jc[r] = __builtin_amdgcn_readlane(jn, tile * ROWS + r);

        // stage tile into LDS (compiler inserts the vmcnt drain)
#pragma unroll
        for (int r = 0; r < ROWS; ++r)
            buf[r * 64 + lane] = ld[r];

        // issue next tile's gathers -- latency hides under this tile's compute
        if (tile + 1 < ntiles) {
            int nb = (tile + 1) * ROWS;
#pragma unroll
            for (int r = 0; r < ROWS; ++r) {
                int n = __builtin_amdgcn_readlane(nn, nb + r);
                ld[r] = x[(size_t)n * IN_CH + lane];
            }
        }

        // wave-private LDS: no barrier needed, just drain ds_writes
        asm volatile("s_waitcnt lgkmcnt(0)" ::: "memory");

#pragma unroll
        for (int r = 0; r < ROWS; r += 2) {
            int grow = tile * ROWS + r;
            float s0 = row_dot(buf, r,     jc[r],     Wl, o, h);
            float s1 = row_dot(buf, r + 1, jc[r + 1], Wl, o, h);
            // both half-waves store: h=0 -> row grow, h=1 -> row grow+1 (256B)
            float sv   = h ? s1 : s0;
            int   orow = grow + h;
            if (orow < nrows)
                out[(size_t)(base + orow) * OUT_CH + o] = sv;
        }
    }
}

extern "C" void kernel_launch(void* const* d_in, const int* in_sizes, int n_in,
                              void* d_out, int out_size, void* d_ws, size_t ws_size,
                              hipStream_t stream) {
    const float* x    = (const float*)d_in[0];
    const float* w    = (const float*)d_in[1];
    const int*   pair = (const int*)d_in[2];
    int N = in_sizes[0] / IN_CH;     // 400000
    int M = out_size / OUT_CH;       // 200000

    char*     ws     = (char*)d_ws;
    int*      argmax = (int*)ws;
    unsigned* wt     = (unsigned*)(ws + (size_t)M * 4);

    int n4 = M / 4;                  // M % 4 == 0
    k_prep<<<(n4 + 255) / 256, 256, 0, stream>>>(w, wt, (int4*)argmax, n4);

    int gN = (N + 255) / 256;
    k_scatter_range<<<gN, 256, 0, stream>>>(pair, argmax, N, 7, 7, 1); // j=7, high-t first
    k_scatter_range<<<gN, 256, 0, stream>>>(pair, argmax, N, 6, 0, 0); // rest, filtered

    int waves  = (M + 63) / 64;
    int blocks = (waves + 7) / 8;
    k_compute<<<blocks, 512, 0, stream>>>(x, (const uint4*)wt, argmax,
                                          (float*)d_out, M, N);
}